// Round 1
// 463.230 us; speedup vs baseline: 1.5461x; 1.5461x over previous
//
#include <hip/hip_runtime.h>
#include <math.h>

#define Bn 256
#define Cc 3
#define Hh 256
#define Ww 256
#define HW (Hh*Ww)        // 65536
#define CHW (Cc*HW)       // 196608

// ws layout (floats): [0..255] per-image sums, then per-image params stride 10
#define P_BASE 256
#define P_STRIDE 10
// param indices: 0 cth, 1 sth, 2 flip, 3 startY, 4 scaleY, 5 startX, 6 scaleX,
//                7 delta, 8 mag1, 9 mag2

#define TS 16             // output tile
#define RY 29             // L1 staged rows (rotated bbox of 18x18 patch)
#define RXS 33            // L1 col stride: 32 loaded cols + 1 pad (odd stride ->
                          // bank = (row+col)%32, conflict-free for any rotation walk)
#define PLANE1 (RY*RXS)           // 957
#define N1 (Cc*PLANE1)            // 2871 floats = 11484 B
#define S2 18             // stage-2 patch dim (17 + 1 fp-edge guard row/col)
#define S2S 20            // stage-2 LDS row stride
#define PLANE2 (S2*S2S)           // 360

__global__ void setup_params(const float* __restrict__ th, const float* __restrict__ fl,
                             const float* __restrict__ sz, const float* __restrict__ sh,
                             const float* __restrict__ de, const float* __restrict__ m1,
                             const float* __restrict__ m2, float* __restrict__ ws) {
    int b = threadIdx.x;   // one thread per image
    ws[b] = 0.0f;          // zero the sum slot (ws poisoned 0xAA each launch)
    float* p = ws + P_BASE + b * P_STRIDE;
    float theta = (th[b] * 2.0f - 1.0f) * 3.14159265358979323846f;  // ROT_DEG=180 -> pi
    p[0] = cosf(theta);
    p[1] = sinf(theta);
    p[2] = (fl[b] > 0.5f) ? 1.0f : 0.0f;
    #pragma unroll
    for (int d = 0; d < 2; d++) {   // d=0 -> y (rows), d=1 -> x (cols)
        float s     = rintf(256.0f * (sz[b*2 + d] * 0.25f + 1.0f) - 0.5f); // jnp.round = rint
        float ms    = s - 256.0f;
        float sr    = ms - 1e-5f;
        float shf   = rintf(sh[b*2 + d] * sr - sr * 0.5f);
        float start = floorf(ms * 0.5f) + shf;
        p[3 + 2*d]  = start;
        p[4 + 2*d]  = 255.0f / (s - 1.0f);
    }
    p[7] = (de[b] * 2.0f - 1.0f) * 0.3f;
    p[8] = (m1[b] * 2.0f - 1.0f) * 0.3f + 1.0f;
    p[9] = (m2[b] * 2.0f - 1.0f) * 0.3f + 1.0f;
}

__global__ __launch_bounds__(256)
void augment_main(const float* __restrict__ img, const float* __restrict__ wsp,
                  float* __restrict__ out, float* __restrict__ sums) {
    __shared__ float L1[N1];        // rotated-source staging, x4-aligned origin (11484 B)
    __shared__ float L2[Cc*PLANE2]; // stage-2 patch 18x18, stride 20 (4320 B)
    __shared__ float wred[4];

    const int tid = threadIdx.x;

    // XCD-contiguous swizzle: dispatch round-robins linear block id across the 8
    // XCD L2s; remap so each XCD owns a contiguous run of tiles (bijective:
    // 65536 % 8 == 0). Neighboring tiles share ~3.3x overlap in the staged
    // region -> keep them on one XCD's L2.
    const int lin = blockIdx.x + (blockIdx.y << 4) + (blockIdx.z << 8);
    const int nid = (lin & 7) * (65536 / 8) + (lin >> 3);
    const int b     = nid >> 8;
    const int tileY = ((nid >> 4) & 15) << 4;
    const int tileX = (nid & 15) << 4;

    const float* p = wsp + P_BASE + b * P_STRIDE;
    const float cth = p[0], sth = p[1];
    const bool  flip = p[2] > 0.5f;
    const float startY = p[3], scaleY = p[4];
    const float startX = p[5], scaleX = p[6];
    const float delta = p[7], mag1 = p[8];

    // ---- stage-2 patch origin (crop-resize source rows/cols for this tile) ----
    float sy0 = fminf(fmaxf((startY + (float)tileY) * scaleY, 0.0f), 255.0f);
    float sx0 = fminf(fmaxf((startX + (float)tileX) * scaleX, 0.0f), 255.0f);
    const int rY = (int)floorf(sy0);
    const int rX = (int)floorf(sx0);

    // ---- rotated bbox of the stage-1 coords needed for the 18x18 patch ----
    const int Ymax = min(rY + S2 - 1, 255);
    const int Xt1  = min(rX + S2 - 1, 255);
    const int Xf0  = flip ? 255 - Xt1 : rX;
    const int Xf1  = flip ? 255 - rX  : Xt1;
    // xg = (2X+1)/256 - 1 = X*(1/128) + (1/256 - 1), exact in fp32
    const float xg0 = fmaf((float)Xf0, 0.0078125f, -0.99609375f);
    const float xg1 = fmaf((float)Xf1, 0.0078125f, -0.99609375f);
    const float yg0 = fmaf((float)rY,  0.0078125f, -0.99609375f);
    const float yg1 = fmaf((float)Ymax,0.0078125f, -0.99609375f);

    float ixmin = 1e30f, iymin = 1e30f;
    #pragma unroll
    for (int cy = 0; cy < 2; cy++) {
        #pragma unroll
        for (int cx = 0; cx < 2; cx++) {
            float xg = cx ? xg1 : xg0;
            float yg = cy ? yg1 : yg0;
            float xp = cth * xg - sth * yg;
            float yp = sth * xg + cth * yg;
            ixmin = fminf(ixmin, fmaf(xp, 128.0f, 127.5f));
            iymin = fminf(iymin, fmaf(yp, 128.0f, 127.5f));
        }
    }
    // UNclamped origins: x0f-bx0 in [0,27], y0f-by0 in [0,27] by construction.
    const int bx0 = (int)floorf(ixmin) - 1;
    const int by0 = (int)floorf(iymin) - 1;
    // x4-aligned x-origin: ax = x0 - bx0a in [0,30] (+1 tap -> 31 <= 31 OK)
    const int bx0a = bx0 & ~3;

    // ---- Phase A: load 29 rows x 32 cols x 3 ch into LDS, one pass, no div ----
    // row = tid>>3 (0..31, rows >=29 idle), col4 = (tid&7)*4 -> float4 loads.
    // y clamps per row (free); x fast path when whole 32-col span is in-bounds
    // (block-uniform branch), else 4 clamped scalar loads per thread.
    const float* imgb = img + (size_t)b * CHW;
    {
        const int r  = tid >> 3;
        const int c4 = (tid & 7) << 2;
        if (r < RY) {
            const int ry = min(max(by0 + r, 0), 255);
            const float* srow = imgb + (ry << 8);
            float* drow = L1 + r * RXS + c4;
            if (bx0a >= 0 && bx0a <= 224) {
                const float* s0 = srow + bx0a + c4;
                #pragma unroll
                for (int ch = 0; ch < Cc; ch++) {
                    float4 v = *(const float4*)(s0 + (ch << 16));
                    float* d = drow + ch * PLANE1;
                    d[0] = v.x; d[1] = v.y; d[2] = v.z; d[3] = v.w;
                }
            } else {
                #pragma unroll
                for (int j = 0; j < 4; j++) {
                    int gx = min(max(bx0a + c4 + j, 0), 255);
                    #pragma unroll
                    for (int ch = 0; ch < Cc; ch++)
                        drow[ch * PLANE1 + j] = srow[(ch << 16) + gx];
                }
            }
        }
    }
    __syncthreads();

    // ---- Phase B: rotate (+flip remap) -> 18x18 stage-2 patch in LDS ----
    for (int i = tid; i < S2 * S2; i += 256) {
        int lY = i / S2;
        int lX = i - lY * S2;
        int Yc = min(rY + lY, 255);
        int Xc = min(rX + lX, 255);
        int Xf = flip ? 255 - Xc : Xc;
        float xg = fmaf((float)Xf, 0.0078125f, -0.99609375f);
        float yg = fmaf((float)Yc, 0.0078125f, -0.99609375f);
        float xp = cth * xg - sth * yg;
        float yp = sth * xg + cth * yg;
        float ixf = fmaf(xp, 128.0f, 127.5f);
        float iyf = fmaf(yp, 128.0f, 127.5f);
        float x0f = floorf(ixf), y0f = floorf(iyf);
        float fx = ixf - x0f, fy = iyf - y0f;
        // zeros-pad validity folded into weights (float-coord test, as reference)
        float wx0 = (x0f >=  0.0f && x0f <= 255.0f) ? (1.0f - fx) : 0.0f;
        float wx1 = (x0f >= -1.0f && x0f <= 254.0f) ? fx          : 0.0f;
        float wy0 = (y0f >=  0.0f && y0f <= 255.0f) ? (1.0f - fy) : 0.0f;
        float wy1 = (y0f >= -1.0f && y0f <= 254.0f) ? fy          : 0.0f;
        int ax = (int)x0f - bx0a;   // in [0,30] by construction
        int ay = (int)y0f - by0;    // in [0,27]
        int ib = ay * RXS + ax;
        float w00 = wy0 * wx0, w01 = wy0 * wx1, w10 = wy1 * wx0, w11 = wy1 * wx1;
        int ob = lY * S2S + lX;
        #pragma unroll
        for (int c = 0; c < Cc; c++) {
            const float* Lc = L1 + c * PLANE1;
            // pairs [ib],[ib+1] and [ib+RXS],[ib+RXS+1] -> ds_read2_b32
            float v = w00 * Lc[ib]       + w01 * Lc[ib + 1]
                    + w10 * Lc[ib + RXS] + w11 * Lc[ib + RXS + 1];
            L2[c * PLANE2 + ob] = v;
        }
    }
    __syncthreads();

    // ---- Phase C: crop-resize bilinear (clamp mode) + color ops + sum ----
    const int py = tid >> 4, px = tid & 15;
    const int y = tileY + py, x = tileX + px;
    float sy = fminf(fmaxf((startY + (float)y) * scaleY, 0.0f), 255.0f);
    float sx = fminf(fmaxf((startX + (float)x) * scaleX, 0.0f), 255.0f);
    float y0f = floorf(sy), x0f = floorf(sx);
    float fy = sy - y0f, fx = sx - x0f;
    int ly = (int)y0f - rY;    // in [0,16]; +1 row exists (S2=18, clamp-replicated)
    int lx = (int)x0f - rX;
    int ib2 = ly * S2S + lx;
    float w00 = (1.0f - fy) * (1.0f - fx), w01 = (1.0f - fy) * fx;
    float w10 = fy * (1.0f - fx),          w11 = fy * fx;

    float x4[3];
    #pragma unroll
    for (int c = 0; c < Cc; c++) {
        const float* Lc = L2 + c * PLANE2;
        float v = w00 * Lc[ib2]       + w01 * Lc[ib2 + 1]
                + w10 * Lc[ib2 + S2S] + w11 * Lc[ib2 + S2S + 1];
        x4[c] = v + delta;
    }
    float mc = (x4[0] + x4[1] + x4[2]) * (1.0f/3.0f);
    float s5 = 0.0f;
    float* outb = out + (size_t)b * CHW + (y << 8) + x;
    #pragma unroll
    for (int c = 0; c < Cc; c++) {
        float v5 = (x4[c] - mc) * mag1 + mc;
        outb[c * HW] = v5;
        s5 += v5;
    }
    // block reduction of sum(x5)
    #pragma unroll
    for (int off = 32; off > 0; off >>= 1) s5 += __shfl_down(s5, off, 64);
    int lane = tid & 63, wid = tid >> 6;
    if (lane == 0) wred[wid] = s5;
    __syncthreads();
    if (tid == 0) atomicAdd(&sums[b], wred[0] + wred[1] + wred[2] + wred[3]);
}

__global__ __launch_bounds__(256)
void finalize_k(float* __restrict__ out, const float* __restrict__ wsp) {
    const int b = blockIdx.y;
    const float m    = wsp[b] * (1.0f / (float)CHW);
    const float mag2 = wsp[P_BASE + b * P_STRIDE + 9];
    float4* ob = (float4*)(out + (size_t)b * CHW);
    int idx = blockIdx.x * 256 + threadIdx.x;
    float4 v = ob[idx];
    v.x = (v.x - m) * mag2 + m;
    v.y = (v.y - m) * mag2 + m;
    v.z = (v.z - m) * mag2 + m;
    v.w = (v.w - m) * mag2 + m;
    ob[idx] = v;
}

extern "C" void kernel_launch(void* const* d_in, const int* in_sizes, int n_in,
                              void* d_out, int out_size, void* d_ws, size_t ws_size,
                              hipStream_t stream) {
    const float* img = (const float*)d_in[0];
    const float* th  = (const float*)d_in[1];
    const float* fl  = (const float*)d_in[2];
    const float* sz  = (const float*)d_in[3];
    const float* sh  = (const float*)d_in[4];
    const float* de  = (const float*)d_in[5];
    const float* m1  = (const float*)d_in[6];
    const float* m2  = (const float*)d_in[7];
    float* out = (float*)d_out;
    float* ws  = (float*)d_ws;

    hipLaunchKernelGGL(setup_params, dim3(1), dim3(256), 0, stream,
                       th, fl, sz, sh, de, m1, m2, ws);
    hipLaunchKernelGGL(augment_main, dim3(Ww/TS, Hh/TS, Bn), dim3(256), 0, stream,
                       img, ws, out, ws);
    hipLaunchKernelGGL(finalize_k, dim3(CHW/4/256, Bn), dim3(256), 0, stream,
                       out, ws);
}

// Round 2
// 451.556 us; speedup vs baseline: 1.5860x; 1.0259x over previous
//
#include <hip/hip_runtime.h>
#include <math.h>

#define Bn 256
#define Cc 3
#define Hh 256
#define Ww 256
#define HW (Hh*Ww)        // 65536
#define CHW (Cc*HW)       // 196608

// ws layout (floats): [0..255] per-image sums, then per-image params stride 10
#define P_BASE 256
#define P_STRIDE 10
// param indices: 0 cth, 1 sth, 2 flip, 3 startY, 4 scaleY, 5 startX, 6 scaleX,
//                7 delta, 8 mag1, 9 mag2

#define TS 16             // output tile
#define RY 29             // L1 staged rows (rotated bbox of 18x18 patch)
#define RXS 33            // L1 col stride: 32 loaded cols + 1 pad (odd stride ->
                          // bank = (row+col)%32; with per-image mirror the lane
                          // walk's bank step is max(|c+s|,|c-s|) >= 1 always)
#define PLANE1 (RY*RXS)           // 957
#define N1 (Cc*PLANE1)            // 2871 floats = 11484 B
#define S2 18             // stage-2 patch dim (17 + 1 fp-edge guard row/col)
#define S2S 20            // stage-2 LDS row stride
#define PLANE2 (S2*S2S)           // 360

__global__ void setup_params(const float* __restrict__ th, const float* __restrict__ fl,
                             const float* __restrict__ sz, const float* __restrict__ sh,
                             const float* __restrict__ de, const float* __restrict__ m1,
                             const float* __restrict__ m2, float* __restrict__ ws) {
    int b = threadIdx.x;   // one thread per image
    ws[b] = 0.0f;          // zero the sum slot (ws poisoned 0xAA each launch)
    float* p = ws + P_BASE + b * P_STRIDE;
    float theta = (th[b] * 2.0f - 1.0f) * 3.14159265358979323846f;  // ROT_DEG=180 -> pi
    p[0] = cosf(theta);
    p[1] = sinf(theta);
    p[2] = (fl[b] > 0.5f) ? 1.0f : 0.0f;
    #pragma unroll
    for (int d = 0; d < 2; d++) {   // d=0 -> y (rows), d=1 -> x (cols)
        float s     = rintf(256.0f * (sz[b*2 + d] * 0.25f + 1.0f) - 0.5f); // jnp.round = rint
        float ms    = s - 256.0f;
        float sr    = ms - 1e-5f;
        float shf   = rintf(sh[b*2 + d] * sr - sr * 0.5f);
        float start = floorf(ms * 0.5f) + shf;
        p[3 + 2*d]  = start;
        p[4 + 2*d]  = 255.0f / (s - 1.0f);
    }
    p[7] = (de[b] * 2.0f - 1.0f) * 0.3f;
    p[8] = (m1[b] * 2.0f - 1.0f) * 0.3f + 1.0f;
    p[9] = (m2[b] * 2.0f - 1.0f) * 0.3f + 1.0f;
}

// Phase B body. MIR/INTR are compile-time (block-uniform dispatch below).
// MIR: L1 stored x-mirrored (sx = 31-ax); taps keep the {0,1,RXS,RXS+1}
// ds_read2 pattern, only x-weights swap. INTR: skip zeros-pad validity selects.
#define PHASE_B_LOOP(MIR, INTR)                                               \
    for (int i = tid; i < S2 * S2; i += 256) {                                \
        int lY = i / S2;                                                      \
        int lX = i - lY * S2;                                                 \
        int Yc = min(rY + lY, 255);                                           \
        int Xc = min(rX + lX, 255);                                           \
        int Xf = flip ? 255 - Xc : Xc;                                        \
        float xg = fmaf((float)Xf, 0.0078125f, -0.99609375f);                 \
        float yg = fmaf((float)Yc, 0.0078125f, -0.99609375f);                 \
        float xp = cth * xg - sth * yg;                                       \
        float yp = sth * xg + cth * yg;                                       \
        float ixf = fmaf(xp, 128.0f, 127.5f);                                 \
        float iyf = fmaf(yp, 128.0f, 127.5f);                                 \
        float x0f = floorf(ixf), y0f = floorf(iyf);                           \
        float fx = ixf - x0f, fy = iyf - y0f;                                 \
        float wx0, wx1, wy0, wy1;                                             \
        if (INTR) {                                                           \
            wx0 = 1.0f - fx; wx1 = fx; wy0 = 1.0f - fy; wy1 = fy;             \
        } else {                                                              \
            wx0 = (x0f >=  0.0f && x0f <= 255.0f) ? (1.0f - fx) : 0.0f;       \
            wx1 = (x0f >= -1.0f && x0f <= 254.0f) ? fx          : 0.0f;       \
            wy0 = (y0f >=  0.0f && y0f <= 255.0f) ? (1.0f - fy) : 0.0f;       \
            wy1 = (y0f >= -1.0f && y0f <= 254.0f) ? fy          : 0.0f;       \
        }                                                                     \
        int ax = (int)x0f - bx0a;   /* in [0,30] by construction */           \
        int ay = (int)y0f - by0;    /* in [0,27] */                           \
        int base = ay * RXS + (MIR ? (30 - ax) : ax);                         \
        float A0 = MIR ? wx1 : wx0;   /* x-weight for L[base] */              \
        float A1 = MIR ? wx0 : wx1;                                           \
        float w00 = wy0 * A0, w01 = wy0 * A1;                                 \
        float w10 = wy1 * A0, w11 = wy1 * A1;                                 \
        int ob = lY * S2S + lX;                                               \
        _Pragma("unroll")                                                     \
        for (int c = 0; c < Cc; c++) {                                        \
            const float* Lc = L1 + c * PLANE1;                                \
            float v = w00 * Lc[base]       + w01 * Lc[base + 1]               \
                    + w10 * Lc[base + RXS] + w11 * Lc[base + RXS + 1];        \
            L2[c * PLANE2 + ob] = v;                                          \
        }                                                                     \
    }

__global__ __launch_bounds__(256)
void augment_main(const float* __restrict__ img, const float* __restrict__ wsp,
                  float* __restrict__ out, float* __restrict__ sums) {
    __shared__ float L1[N1];        // rotated-source staging (11484 B)
    __shared__ float L2[Cc*PLANE2]; // stage-2 patch 18x18, stride 20 (4320 B)
    __shared__ float wred[4];

    const int tid = threadIdx.x;

    // XCD-contiguous swizzle (bijective: 65536 % 8 == 0): each XCD owns a
    // contiguous run of tiles so the ~3.3x staged-region overlap hits its L2.
    const int lin = blockIdx.x + (blockIdx.y << 4) + (blockIdx.z << 8);
    const int nid = (lin & 7) * (65536 / 8) + (lin >> 3);
    const int b     = nid >> 8;
    const int tileY = ((nid >> 4) & 15) << 4;
    const int tileX = (nid & 15) << 4;

    const float* p = wsp + P_BASE + b * P_STRIDE;
    const float cth = p[0], sth = p[1];
    const bool  flip = p[2] > 0.5f;
    const float startY = p[3], scaleY = p[4];
    const float startX = p[5], scaleX = p[6];
    const float delta = p[7], mag1 = p[8];
    // mirror the L1 x-axis when cos*sin < 0: bank step along the rotated lane
    // walk becomes max(|c+s|,|c-s|) >= 1 -> kills the 16..32-way conflict tail.
    const bool mir = (cth * sth) < 0.0f;

    // ---- stage-2 patch origin (crop-resize source rows/cols for this tile) ----
    float sy0 = fminf(fmaxf((startY + (float)tileY) * scaleY, 0.0f), 255.0f);
    float sx0 = fminf(fmaxf((startX + (float)tileX) * scaleX, 0.0f), 255.0f);
    const int rY = (int)floorf(sy0);
    const int rX = (int)floorf(sx0);

    // ---- rotated bbox of the stage-1 coords needed for the 18x18 patch ----
    const int Ymax = min(rY + S2 - 1, 255);
    const int Xt1  = min(rX + S2 - 1, 255);
    const int Xf0  = flip ? 255 - Xt1 : rX;
    const int Xf1  = flip ? 255 - rX  : Xt1;
    // xg = (2X+1)/256 - 1 = X*(1/128) + (1/256 - 1), exact in fp32
    const float xg0 = fmaf((float)Xf0, 0.0078125f, -0.99609375f);
    const float xg1 = fmaf((float)Xf1, 0.0078125f, -0.99609375f);
    const float yg0 = fmaf((float)rY,  0.0078125f, -0.99609375f);
    const float yg1 = fmaf((float)Ymax,0.0078125f, -0.99609375f);

    float ixmin = 1e30f, iymin = 1e30f, ixmax = -1e30f, iymax = -1e30f;
    #pragma unroll
    for (int cy = 0; cy < 2; cy++) {
        #pragma unroll
        for (int cx = 0; cx < 2; cx++) {
            float xg = cx ? xg1 : xg0;
            float yg = cy ? yg1 : yg0;
            float xp = cth * xg - sth * yg;
            float yp = sth * xg + cth * yg;
            float tx = fmaf(xp, 128.0f, 127.5f);
            float ty = fmaf(yp, 128.0f, 127.5f);
            ixmin = fminf(ixmin, tx); ixmax = fmaxf(ixmax, tx);
            iymin = fminf(iymin, ty); iymax = fmaxf(iymax, ty);
        }
    }
    // UNclamped origins: x0f-bx0 in [0,27], y0f-by0 in [0,27] by construction.
    const int bx0 = (int)floorf(ixmin) - 1;
    const int by0 = (int)floorf(iymin) - 1;
    // x4-aligned x-origin: ax = x0 - bx0a in [0,30] (+1 tap -> 31 <= 31 OK)
    const int bx0a = bx0 & ~3;
    // theta-dependent trims: only rows [0,rneed) / cols [0,cneed) are touched
    const int rneed = min(RY, (int)floorf(iymax) - by0 + 2);
    const int cneed = (int)floorf(ixmax) - bx0a + 2;   // <= 32
    // all zeros-pad validity tests pass for every Phase-B site?
    const bool interior = (ixmin >= 0.0f) && (iymin >= 0.0f) &&
                          (ixmax < 255.0f) && (iymax < 255.0f);

    // ---- Phase A: load rneed rows x cneed cols x 3 ch into LDS ----
    // row = tid>>3 (0..31), col4 = (tid&7)*4 -> float4 loads, no int div.
    const float* imgb = img + (size_t)b * CHW;
    {
        const int r  = tid >> 3;
        const int c4 = (tid & 7) << 2;
        if (r < rneed && c4 < cneed) {
            const int ry = min(max(by0 + r, 0), 255);
            const float* srow = imgb + (ry << 8);
            if (bx0a >= 0 && bx0a <= 224) {
                const float* s0 = srow + bx0a + c4;
                if (!mir) {
                    float* d = L1 + r * RXS + c4;
                    #pragma unroll
                    for (int ch = 0; ch < Cc; ch++) {
                        float4 v = *(const float4*)(s0 + (ch << 16));
                        float* dd = d + ch * PLANE1;
                        dd[0] = v.x; dd[1] = v.y; dd[2] = v.z; dd[3] = v.w;
                    }
                } else {
                    float* d = L1 + r * RXS + (28 - c4);  // sx = 31-(c4+j)
                    #pragma unroll
                    for (int ch = 0; ch < Cc; ch++) {
                        float4 v = *(const float4*)(s0 + (ch << 16));
                        float* dd = d + ch * PLANE1;
                        dd[0] = v.w; dd[1] = v.z; dd[2] = v.y; dd[3] = v.x;
                    }
                }
            } else {
                #pragma unroll
                for (int j = 0; j < 4; j++) {
                    int gx = min(max(bx0a + c4 + j, 0), 255);
                    int sx = mir ? (31 - (c4 + j)) : (c4 + j);
                    #pragma unroll
                    for (int ch = 0; ch < Cc; ch++)
                        L1[ch * PLANE1 + r * RXS + sx] = srow[(ch << 16) + gx];
                }
            }
        }
    }
    __syncthreads();

    // ---- Phase B: rotate (+flip remap) -> 18x18 stage-2 patch in LDS ----
    if (interior) {
        if (mir) { PHASE_B_LOOP(true,  true) } else { PHASE_B_LOOP(false, true) }
    } else {
        if (mir) { PHASE_B_LOOP(true,  false) } else { PHASE_B_LOOP(false, false) }
    }
    __syncthreads();

    // ---- Phase C: crop-resize bilinear (clamp mode) + color ops + sum ----
    const int py = tid >> 4, px = tid & 15;
    const int y = tileY + py, x = tileX + px;
    float sy = fminf(fmaxf((startY + (float)y) * scaleY, 0.0f), 255.0f);
    float sx = fminf(fmaxf((startX + (float)x) * scaleX, 0.0f), 255.0f);
    float y0f = floorf(sy), x0f = floorf(sx);
    float fy = sy - y0f, fx = sx - x0f;
    int ly = (int)y0f - rY;    // in [0,16]; +1 row exists (S2=18, clamp-replicated)
    int lx = (int)x0f - rX;
    int ib2 = ly * S2S + lx;
    float w00 = (1.0f - fy) * (1.0f - fx), w01 = (1.0f - fy) * fx;
    float w10 = fy * (1.0f - fx),          w11 = fy * fx;

    float vv[3];
    #pragma unroll
    for (int c = 0; c < Cc; c++) {
        const float* Lc = L2 + c * PLANE2;
        vv[c] = w00 * Lc[ib2]       + w01 * Lc[ib2 + 1]
              + w10 * Lc[ib2 + S2S] + w11 * Lc[ib2 + S2S + 1];
    }
    // v5 = ((v+delta) - mean(v+delta))*mag1 + mean(v+delta)
    //    = fma(v, mag1, mc*(1-mag1) + delta)
    float mc  = (vv[0] + vv[1] + vv[2]) * (1.0f/3.0f);
    float mck = fmaf(-mag1, mc, mc) + delta;
    float s5 = 0.0f;
    float* outb = out + (size_t)b * CHW + (y << 8) + x;
    #pragma unroll
    for (int c = 0; c < Cc; c++) {
        float v5 = fmaf(vv[c], mag1, mck);
        outb[c * HW] = v5;
        s5 += v5;
    }
    // block reduction of sum(x5)
    #pragma unroll
    for (int off = 32; off > 0; off >>= 1) s5 += __shfl_down(s5, off, 64);
    int lane = tid & 63, wid = tid >> 6;
    if (lane == 0) wred[wid] = s5;
    __syncthreads();
    if (tid == 0) atomicAdd(&sums[b], wred[0] + wred[1] + wred[2] + wred[3]);
}

__global__ __launch_bounds__(256)
void finalize_k(float* __restrict__ out, const float* __restrict__ wsp) {
    const int b = blockIdx.y;
    const float m    = wsp[b] * (1.0f / (float)CHW);
    const float mag2 = wsp[P_BASE + b * P_STRIDE + 9];
    float4* ob = (float4*)(out + (size_t)b * CHW);
    int idx = blockIdx.x * 256 + threadIdx.x;
    float4 v = ob[idx];
    v.x = (v.x - m) * mag2 + m;
    v.y = (v.y - m) * mag2 + m;
    v.z = (v.z - m) * mag2 + m;
    v.w = (v.w - m) * mag2 + m;
    ob[idx] = v;
}

extern "C" void kernel_launch(void* const* d_in, const int* in_sizes, int n_in,
                              void* d_out, int out_size, void* d_ws, size_t ws_size,
                              hipStream_t stream) {
    const float* img = (const float*)d_in[0];
    const float* th  = (const float*)d_in[1];
    const float* fl  = (const float*)d_in[2];
    const float* sz  = (const float*)d_in[3];
    const float* sh  = (const float*)d_in[4];
    const float* de  = (const float*)d_in[5];
    const float* m1  = (const float*)d_in[6];
    const float* m2  = (const float*)d_in[7];
    float* out = (float*)d_out;
    float* ws  = (float*)d_ws;

    hipLaunchKernelGGL(setup_params, dim3(1), dim3(256), 0, stream,
                       th, fl, sz, sh, de, m1, m2, ws);
    hipLaunchKernelGGL(augment_main, dim3(Ww/TS, Hh/TS, Bn), dim3(256), 0, stream,
                       img, ws, out, ws);
    hipLaunchKernelGGL(finalize_k, dim3(CHW/4/256, Bn), dim3(256), 0, stream,
                       out, ws);
}